// Round 11
// baseline (176.556 us; speedup 1.0000x reference)
//
#include <hip/hip_runtime.h>
#include <hip/hip_bf16.h>

#define DIM 128
#define BNODES 64       // fine bucket = 64 dst nodes (dst>>6)
#define CNODES 1024     // coarse bucket = 1024 dst nodes (dst>>10)
#define NCMAX 128       // coarse cursor capacity (ncb = 98 for N=100000)
#define NBMAX 2048      // fine cursor capacity (nb = 1563)
#define CCAP 20480      // edges per coarse region (mean 16327, +32 sigma)
#define BCAP 2048       // edges per fine region (mean 1024, +32 sigma)
#define FB 16           // fine targets per coarse region (CNODES/BNODES)

typedef __attribute__((ext_vector_type(8))) short bf16x8;
typedef __attribute__((ext_vector_type(4))) float f32x4;

__device__ inline ushort f2bf(float f) {
    uint u = __float_as_uint(f);
    u += 0x7fffu + ((u >> 16) & 1u);   // RNE
    return (ushort)(u >> 16);
}
__device__ inline uint pack2(float lo, float hi) {
    return (uint)f2bf(lo) | ((uint)f2bf(hi) << 16);
}

// ---- MFMA linear body (round-3-proven, used for lin1 only now) --------------
// out[n][j] = relu(b[j] + sum_k in[n][k]*W[j][k]); one wave per 16-row tile.
// A/B share an assumed k-bijection (dot invariant); C layout m89-verified:
// col=lane&15, row=(lane>>4)*4+reg. Live set ~104 VGPR (round 6: forcing 4/EU spills).
template<bool BF16OUT>
__device__ __forceinline__
void linear_body(const float* in, const float* __restrict__ W,
                 const float* __restrict__ b, void* outv, int n_tiles,
                 int bid, int nblocks, uint4* Wl)
{
    const int t = threadIdx.x;
    for (int q = t; q < 2048; q += 256) {
        const int j = q >> 4, c = q & 15;
        const float4 lo = ((const float4*)(W + j * 128 + c * 8))[0];
        const float4 hi = ((const float4*)(W + j * 128 + c * 8))[1];
        uint4 pk;
        pk.x = pack2(lo.x, lo.y); pk.y = pack2(lo.z, lo.w);
        pk.z = pack2(hi.x, hi.y); pk.w = pack2(hi.z, hi.w);
        Wl[j * 16 + (c ^ (j & 15))] = pk;
    }
    __syncthreads();

    const int lane = t & 63;
    const int lo4 = lane & 15;
    const int g   = lane >> 4;

    float bias[8];
    #pragma unroll
    for (int ct = 0; ct < 8; ++ct) bias[ct] = b[ct * 16 + lo4];

    const int wid = (bid * 256 + t) >> 6;
    const int nw  = (nblocks * 256) >> 6;

    for (int tile = wid; tile < n_tiles; tile += nw) {
        const int arow = tile * 16 + lo4;
        const float4* ap = (const float4*)(in + (size_t)arow * DIM + g * 32);
        float4 v[8];
        #pragma unroll
        for (int i = 0; i < 8; ++i) v[i] = ap[i];

        bf16x8 afrag[4];
        #pragma unroll
        for (int ks = 0; ks < 4; ++ks) {
            union { bf16x8 v8; uint u[4]; } a;
            a.u[0] = pack2(v[2*ks].x,   v[2*ks].y);
            a.u[1] = pack2(v[2*ks].z,   v[2*ks].w);
            a.u[2] = pack2(v[2*ks+1].x, v[2*ks+1].y);
            a.u[3] = pack2(v[2*ks+1].z, v[2*ks+1].w);
            afrag[ks] = a.v8;
        }

        f32x4 acc[8];
        #pragma unroll
        for (int ct = 0; ct < 8; ++ct)
            acc[ct] = (f32x4){bias[ct], bias[ct], bias[ct], bias[ct]};

        #pragma unroll
        for (int ks = 0; ks < 4; ++ks) {
            #pragma unroll
            for (int ct = 0; ct < 8; ++ct) {
                const int jrow = ct * 16 + lo4;
                const bf16x8 bfrag = *((const bf16x8*)&Wl[jrow * 16 + ((g * 4 + ks) ^ lo4)]);
                acc[ct] = __builtin_amdgcn_mfma_f32_16x16x32_bf16(afrag[ks], bfrag, acc[ct], 0, 0, 0);
            }
        }

        #pragma unroll
        for (int ct = 0; ct < 8; ++ct) {
            #pragma unroll
            for (int r = 0; r < 4; ++r) {
                const int orow = tile * 16 + g * 4 + r;
                const int ocol = ct * 16 + lo4;
                float val = fmaxf(acc[ct][r], 0.f);
                if constexpr (BF16OUT)
                    ((ushort*)outv)[(size_t)orow * DIM + ocol] = f2bf(val);
                else
                    ((float*)outv)[(size_t)orow * DIM + ocol] = val;
            }
        }
    }
}

// ---- fused: coarse partition || lin1 || Wu pre-pack -------------------------
// blocks [0,cb): coarse scatter (latency/atomic);  [cb,cb+lb): lin1 MFMA;
// [cb+lb, cb+lb+8): pack Wu to pre-swizzled bf16 (for the fused gather).
__global__ __launch_bounds__(256, 2)
void lin1_coarse_kernel(const float* x, const float* __restrict__ Wm,
                        const float* __restrict__ bm, ushort* msg, int n_tiles,
                        const int* __restrict__ ei, int* __restrict__ ccur,
                        uint* __restrict__ cedges, int n_edges, int ncb,
                        const float* __restrict__ Wu, uint4* __restrict__ wupk,
                        int cb, int lb)
{
    __shared__ uint4 Wl[128 * 16];   // 32 KB (lin path)
    __shared__ int histL[NCMAX];
    __shared__ int curL[NCMAX];

    const int bid = (int)blockIdx.x;
    if (bid < cb) {
        const int t = threadIdx.x;
        if (t < ncb) histL[t] = 0;
        __syncthreads();
        const int chunk = (n_edges + cb - 1) / cb;
        const int e0 = bid * chunk;
        const int e1 = min(e0 + chunk, n_edges);
        for (int e = e0 + t; e < e1; e += 256)
            atomicAdd(&histL[ei[n_edges + e] >> 10], 1);
        __syncthreads();
        if (t < ncb)
            curL[t] = histL[t] ? atomicAdd(&ccur[t], histL[t]) : 0;
        __syncthreads();
        for (int e = e0 + t; e < e1; e += 256) {
            const int src = ei[e];
            const int dst = ei[n_edges + e];
            const int c = dst >> 10;
            const int pos = atomicAdd(&curL[c], 1);
            if (pos < CCAP)
                cedges[(size_t)c * CCAP + pos] = ((uint)src << 10) | (uint)(dst & 1023);
        }
    } else if (bid < cb + lb) {
        linear_body<true>(x, Wm, bm, msg, n_tiles, bid - cb, lb, Wl);
    } else {
        const int q = (bid - cb - lb) * 256 + (int)threadIdx.x;   // 0..2047
        const int j = q >> 4, c = q & 15;
        const float4 lo = ((const float4*)(Wu + j * 128 + c * 8))[0];
        const float4 hi = ((const float4*)(Wu + j * 128 + c * 8))[1];
        uint4 pk;
        pk.x = pack2(lo.x, lo.y); pk.y = pack2(lo.z, lo.w);
        pk.z = pack2(hi.x, hi.y); pk.w = pack2(hi.z, hi.w);
        wupk[j * 16 + (c ^ (j & 15))] = pk;
    }
}

// Fine pass: refine each coarse region into its 16 fine buckets (dst>>6).
__global__ __launch_bounds__(256)
void fine_scatter_kernel(const int* __restrict__ ccnt, const uint* __restrict__ cedges,
                         int* __restrict__ gcur, uint* __restrict__ bedges, int ncb)
{
    __shared__ int histL[FB];
    __shared__ int curL[FB];
    const int t = threadIdx.x;
    const int c = blockIdx.x >> 3;
    const int s = blockIdx.x & 7;
    const int cnt = min(ccnt[c], CCAP);
    const int chunk = (cnt + 7) / 8;
    const int e0 = s * chunk;
    const int e1 = min(e0 + chunk, cnt);
    if (t < FB) histL[t] = 0;
    __syncthreads();
    const uint* ce = cedges + (size_t)c * CCAP;
    for (int i = e0 + t; i < e1; i += 256)
        atomicAdd(&histL[(ce[i] & 1023u) >> 6], 1);
    __syncthreads();
    if (t < FB)
        curL[t] = histL[t] ? atomicAdd(&gcur[c * FB + t], histL[t]) : 0;
    __syncthreads();
    for (int i = e0 + t; i < e1; i += 256) {
        const uint p = ce[i];
        const uint dl = p & 1023u;
        const int f = (int)(dl >> 6);
        const int pos = atomicAdd(&curL[f], 1);
        if (pos < BCAP)
            bedges[(size_t)(c * FB + f) * BCAP + pos] = ((p >> 10) << 6) | (dl & 63u);
    }
}

// ---- fused gather + lin2 ----------------------------------------------------
// Per 64-node bucket: (a) stage+sort edges in LDS (int atomics), (b) pull:
// one wave per node, coalesced 256B msg reads, fp32 register accumulate,
// deposit row as packed bf16 into chunk-swizzled LDS tile (identical numerics:
// old lin2 converted fp32 agg -> bf16 anyway), (c) barrier, (d) MFMA
// out = relu(agg@Wu^T+bu)+x directly to global. Saves the 102 MB agg
// global round-trip + one dispatch. LDS ~66 KB -> 2 blocks/CU (16 waves).
__global__ __launch_bounds__(512)
void gather_lin2_kernel(const uint* __restrict__ msg, const int* __restrict__ gcur,
                        const uint* __restrict__ bedges, const uint4* __restrict__ wupk,
                        const float* __restrict__ bu, const float* __restrict__ x,
                        float* __restrict__ out, int n_nodes)
{
    __shared__ uint4 Wl[128 * 16];       // 32 KB packed Wu (pre-swizzled)
    __shared__ uint  aggL[BNODES * 64];  // 16 KB bf16 agg tile, chunk-swizzled
    __shared__ uint  edgesL[BCAP];       // 8 KB
    __shared__ int   srcL[BCAP];         // 8 KB
    __shared__ int histL[BNODES];
    __shared__ int inclL[BNODES];
    __shared__ int cursL[BNODES];

    const int t = threadIdx.x;
    const int b = blockIdx.x;
    const int cnt = min(gcur[b], BCAP);
    const uint* be = bedges + (size_t)b * BCAP;

    // stage Wu (1:1 copy, already packed+swizzled)
    for (int q = t; q < 2048; q += 512) Wl[q] = wupk[q];

    if (t < BNODES) histL[t] = 0;
    __syncthreads();
    for (int i = t; i < cnt; i += 512) {
        const uint p = be[i];
        edgesL[i] = p;
        atomicAdd(&histL[p & 63u], 1);
    }
    __syncthreads();
    if (t < BNODES) inclL[t] = histL[t];
    for (int off = 1; off < BNODES; off <<= 1) {
        int add = 0;
        __syncthreads();
        if (t < BNODES && t >= off) add = inclL[t - off];
        __syncthreads();
        if (t < BNODES) inclL[t] += add;
    }
    __syncthreads();
    if (t < BNODES) cursL[t] = inclL[t] - histL[t];
    __syncthreads();
    for (int i = t; i < cnt; i += 512) {
        const uint p = edgesL[i];
        const int pos = atomicAdd(&cursL[p & 63u], 1);
        srcL[pos] = (int)(p >> 6);
    }
    __syncthreads();

    const int lane = t & 63;
    const int w = t >> 6;            // 8 waves

    // (b) pull: wave w owns nodes dl = w, w+8, ...
    for (int dl = w; dl < BNODES; dl += 8) {
        const int node = b * BNODES + dl;
        if (node >= n_nodes) break;          // wave-uniform
        const int e1 = inclL[dl];
        const int e0 = e1 - histL[dl];
        float a0 = 0.f, a1 = 0.f;
        int i = e0;
        for (; i + 4 <= e1; i += 4) {
            const int sA = srcL[i + 0], sB = srcL[i + 1];
            const int sC = srcL[i + 2], sD = srcL[i + 3];
            const uint mA = msg[(size_t)sA * 64 + lane];
            const uint mB = msg[(size_t)sB * 64 + lane];
            const uint mC = msg[(size_t)sC * 64 + lane];
            const uint mD = msg[(size_t)sD * 64 + lane];
            a0 += __uint_as_float(mA << 16) + __uint_as_float(mB << 16)
                + __uint_as_float(mC << 16) + __uint_as_float(mD << 16);
            a1 += __uint_as_float(mA & 0xffff0000u) + __uint_as_float(mB & 0xffff0000u)
                + __uint_as_float(mC & 0xffff0000u) + __uint_as_float(mD & 0xffff0000u);
        }
        for (; i < e1; ++i) {
            const uint m = msg[(size_t)srcL[i] * 64 + lane];
            a0 += __uint_as_float(m << 16);
            a1 += __uint_as_float(m & 0xffff0000u);
        }
        // deposit row dl as bf16: uint col = lane (cols 2*lane, 2*lane+1);
        // 16B-chunk swizzle: chunk' = (lane>>2) ^ (dl&15)
        aggL[dl * 64 + ((((lane >> 2) ^ (dl & 15)) << 2) | (lane & 3))] = pack2(a0, a1);
    }
    __syncthreads();

    // (d) MFMA: wave w -> row-tile tw = w&3, col-half ch = w>>2 (4 col-tiles)
    const int lo4 = lane & 15;
    const int g   = lane >> 4;
    const int tw  = w & 3;
    const int ch  = w >> 2;

    float bias[4];
    #pragma unroll
    for (int ct = 0; ct < 4; ++ct) bias[ct] = bu[(ch * 4 + ct) * 16 + lo4];

    const int arow = tw * 16 + lo4;
    bf16x8 afrag[4];
    #pragma unroll
    for (int ks = 0; ks < 4; ++ks) {
        const int cidx = (g * 4 + ks) ^ (arow & 15);
        afrag[ks] = *(const bf16x8*)&aggL[arow * 64 + cidx * 4];
    }

    f32x4 acc[4];
    #pragma unroll
    for (int ct = 0; ct < 4; ++ct)
        acc[ct] = (f32x4){bias[ct], bias[ct], bias[ct], bias[ct]};

    #pragma unroll
    for (int ks = 0; ks < 4; ++ks) {
        #pragma unroll
        for (int ct = 0; ct < 4; ++ct) {
            const int jrow = (ch * 4 + ct) * 16 + lo4;
            const bf16x8 bfrag = *((const bf16x8*)&Wl[jrow * 16 + ((g * 4 + ks) ^ lo4)]);
            acc[ct] = __builtin_amdgcn_mfma_f32_16x16x32_bf16(afrag[ks], bfrag, acc[ct], 0, 0, 0);
        }
    }

    const int node0 = b * BNODES;
    #pragma unroll
    for (int ct = 0; ct < 4; ++ct) {
        #pragma unroll
        for (int r = 0; r < 4; ++r) {
            const int orow = node0 + tw * 16 + g * 4 + r;
            const int ocol = (ch * 4 + ct) * 16 + lo4;
            if (orow < n_nodes) {
                const float val = fmaxf(acc[ct][r], 0.f) + x[(size_t)orow * DIM + ocol];
                out[(size_t)orow * DIM + ocol] = val;
            }
        }
    }
}

extern "C" void kernel_launch(void* const* d_in, const int* in_sizes, int n_in,
                              void* d_out, int out_size, void* d_ws, size_t ws_size,
                              hipStream_t stream)
{
    const float* x  = (const float*)d_in[0];
    const int*   ei = (const int*)d_in[1];
    const float* Wm = (const float*)d_in[2];
    const float* bm = (const float*)d_in[3];
    const float* Wu = (const float*)d_in[4];
    const float* bu = (const float*)d_in[5];

    const int N = in_sizes[0] / DIM;   // 100000
    const int E = in_sizes[1] / 2;     // 1600000
    const int nb  = (N + BNODES - 1) / BNODES;   // 1563
    const int ncb = (N + CNODES - 1) / CNODES;   // 98

    // ws: msg 25.6MB | ccur+gcur ~8.7KB | wupk 32KB | cedges 8.0MB | bedges 12.8MB
    char* ws = (char*)d_ws;
    ushort* msg = (ushort*)ws;
    size_t o = (size_t)N * DIM * sizeof(ushort);
    int* ccur = (int*)(ws + o); o += (size_t)NCMAX * 4;
    int* gcur = (int*)(ws + o); o += (size_t)NBMAX * 4;
    o = (o + 255) & ~(size_t)255;
    uint4* wupk = (uint4*)(ws + o); o += 2048 * sizeof(uint4);
    o = (o + 255) & ~(size_t)255;
    uint* cedges = (uint*)(ws + o); o += (size_t)ncb * CCAP * 4;
    o = (o + 255) & ~(size_t)255;
    uint* bedges = (uint*)(ws + o);

    float* out = (float*)d_out;
    const int n_tiles = N / 16;

    // 0) zero cursors (ccur and gcur adjacent)
    hipMemsetAsync(ccur, 0, (size_t)(NCMAX + NBMAX) * 4, stream);

    // 1) fused: coarse partition (1024) || lin1 messages (1024) || Wu pack (8)
    lin1_coarse_kernel<<<2056, 256, 0, stream>>>(x, Wm, bm, msg, n_tiles,
                                                 ei, ccur, cedges, E, ncb,
                                                 Wu, wupk, 1024, 1024);

    // 2) fine partition: coarse regions -> 64-node buckets
    fine_scatter_kernel<<<ncb * 8, 256, 0, stream>>>(ccur, cedges, gcur, bedges, ncb);

    // 3) fused gather + update GEMM + residual -> d_out
    gather_lin2_kernel<<<nb, 512, 0, stream>>>((const uint*)msg, gcur, bedges,
                                               (const uint4*)wupk, bu, x, out, N);
}

// Round 12
// 155.808 us; speedup vs baseline: 1.1332x; 1.1332x over previous
//
#include <hip/hip_runtime.h>
#include <hip/hip_bf16.h>

#define DIM 128
#define BNODES 64       // fine bucket = 64 dst nodes (dst>>6)
#define CNODES 1024     // coarse bucket = 1024 dst nodes (dst>>10)
#define NCMAX 128       // coarse cursor capacity (ncb = 98 for N=100000)
#define NBMAX 2048      // fine cursor capacity (nb = 1563)
#define CCAP 20480      // edges per coarse region (mean 16327, +32 sigma)
#define BCAP 2048       // edges per fine region (mean 1024, +32 sigma)
#define FB 16           // fine targets per coarse region (CNODES/BNODES)

typedef __attribute__((ext_vector_type(8))) short bf16x8;
typedef __attribute__((ext_vector_type(4))) float f32x4;

__device__ inline ushort f2bf(float f) {
    uint u = __float_as_uint(f);
    u += 0x7fffu + ((u >> 16) & 1u);   // RNE
    return (ushort)(u >> 16);
}
__device__ inline uint pack2(float lo, float hi) {
    return (uint)f2bf(lo) | ((uint)f2bf(hi) << 16);
}

// ---- MFMA linear body (round-3-proven) --------------------------------------
// out[n][j] = relu(b[j] + sum_k in[n][k]*W[j][k])  (+ xres if RESID)
// One wave per 16-row tile; in-place safe for RESID. A/B share an assumed
// k-bijection (dot invariant); C layout m89-verified: col=lane&15,
// row=(lane>>4)*4+reg. Live set ~104 VGPR (round 6: forcing 4/EU spills).
template<bool RESID, bool BF16OUT>
__device__ __forceinline__
void linear_body(const float* in, const float* __restrict__ W,
                 const float* __restrict__ b, const float* __restrict__ xres,
                 void* outv, int n_tiles, int bid, int nblocks, uint4* Wl)
{
    const int t = threadIdx.x;
    for (int q = t; q < 2048; q += 256) {
        const int j = q >> 4, c = q & 15;
        const float4 lo = ((const float4*)(W + j * 128 + c * 8))[0];
        const float4 hi = ((const float4*)(W + j * 128 + c * 8))[1];
        uint4 pk;
        pk.x = pack2(lo.x, lo.y); pk.y = pack2(lo.z, lo.w);
        pk.z = pack2(hi.x, hi.y); pk.w = pack2(hi.z, hi.w);
        Wl[j * 16 + (c ^ (j & 15))] = pk;
    }
    __syncthreads();

    const int lane = t & 63;
    const int lo4 = lane & 15;
    const int g   = lane >> 4;

    float bias[8];
    #pragma unroll
    for (int ct = 0; ct < 8; ++ct) bias[ct] = b[ct * 16 + lo4];

    const int wid = (bid * 256 + t) >> 6;
    const int nw  = (nblocks * 256) >> 6;

    for (int tile = wid; tile < n_tiles; tile += nw) {
        const int arow = tile * 16 + lo4;
        const float4* ap = (const float4*)(in + (size_t)arow * DIM + g * 32);
        float4 v[8];
        #pragma unroll
        for (int i = 0; i < 8; ++i) v[i] = ap[i];

        bf16x8 afrag[4];
        #pragma unroll
        for (int ks = 0; ks < 4; ++ks) {
            union { bf16x8 v8; uint u[4]; } a;
            a.u[0] = pack2(v[2*ks].x,   v[2*ks].y);
            a.u[1] = pack2(v[2*ks].z,   v[2*ks].w);
            a.u[2] = pack2(v[2*ks+1].x, v[2*ks+1].y);
            a.u[3] = pack2(v[2*ks+1].z, v[2*ks+1].w);
            afrag[ks] = a.v8;
        }

        f32x4 acc[8];
        #pragma unroll
        for (int ct = 0; ct < 8; ++ct)
            acc[ct] = (f32x4){bias[ct], bias[ct], bias[ct], bias[ct]};

        #pragma unroll
        for (int ks = 0; ks < 4; ++ks) {
            #pragma unroll
            for (int ct = 0; ct < 8; ++ct) {
                const int jrow = ct * 16 + lo4;
                const bf16x8 bfrag = *((const bf16x8*)&Wl[jrow * 16 + ((g * 4 + ks) ^ lo4)]);
                acc[ct] = __builtin_amdgcn_mfma_f32_16x16x32_bf16(afrag[ks], bfrag, acc[ct], 0, 0, 0);
            }
        }

        #pragma unroll
        for (int ct = 0; ct < 8; ++ct) {
            #pragma unroll
            for (int r = 0; r < 4; ++r) {
                const int orow = tile * 16 + g * 4 + r;
                const int ocol = ct * 16 + lo4;
                float val = fmaxf(acc[ct][r], 0.f);
                if constexpr (RESID) val += xres[(size_t)orow * DIM + ocol];
                if constexpr (BF16OUT)
                    ((ushort*)outv)[(size_t)orow * DIM + ocol] = f2bf(val);
                else
                    ((float*)outv)[(size_t)orow * DIM + ocol] = val;
            }
        }
    }
}

// ---- fused: coarse partition (blocks [0,cb)) || lin1 (rest) -----------------
__global__ __launch_bounds__(256, 2)
void lin1_coarse_kernel(const float* x, const float* __restrict__ Wm,
                        const float* __restrict__ bm, ushort* msg, int n_tiles,
                        const int* __restrict__ ei, int* __restrict__ ccur,
                        uint* __restrict__ cedges, int n_edges, int ncb, int cb)
{
    __shared__ uint4 Wl[128 * 16];   // 32 KB (lin path)
    __shared__ int histL[NCMAX];
    __shared__ int curL[NCMAX];

    const int bid = (int)blockIdx.x;
    if (bid < cb) {
        const int t = threadIdx.x;
        if (t < ncb) histL[t] = 0;
        __syncthreads();
        const int chunk = (n_edges + cb - 1) / cb;
        const int e0 = bid * chunk;
        const int e1 = min(e0 + chunk, n_edges);
        for (int e = e0 + t; e < e1; e += 256)
            atomicAdd(&histL[ei[n_edges + e] >> 10], 1);
        __syncthreads();
        if (t < ncb)
            curL[t] = histL[t] ? atomicAdd(&ccur[t], histL[t]) : 0;
        __syncthreads();
        for (int e = e0 + t; e < e1; e += 256) {
            const int src = ei[e];
            const int dst = ei[n_edges + e];
            const int c = dst >> 10;
            const int pos = atomicAdd(&curL[c], 1);
            if (pos < CCAP)
                cedges[(size_t)c * CCAP + pos] = ((uint)src << 10) | (uint)(dst & 1023);
        }
    } else {
        linear_body<false, true>(x, Wm, bm, nullptr, msg, n_tiles,
                                 bid - cb, (int)gridDim.x - cb, Wl);
    }
}

__global__ __launch_bounds__(256, 2)
void lin2_kernel(const float* agg, const float* __restrict__ Wu,
                 const float* __restrict__ bu, const float* __restrict__ x,
                 float* out, int n_tiles)
{
    __shared__ uint4 Wl[128 * 16];
    linear_body<true, false>(agg, Wu, bu, x, out, n_tiles,
                             (int)blockIdx.x, (int)gridDim.x, Wl);
}

// Fine pass: refine each coarse region into its 16 fine buckets (dst>>6).
// Contiguous reads, ~1KB write runs. grid = ncb*8.
__global__ __launch_bounds__(256)
void fine_scatter_kernel(const int* __restrict__ ccnt, const uint* __restrict__ cedges,
                         int* __restrict__ gcur, uint* __restrict__ bedges, int ncb)
{
    __shared__ int histL[FB];
    __shared__ int curL[FB];
    const int t = threadIdx.x;
    const int c = blockIdx.x >> 3;
    const int s = blockIdx.x & 7;
    const int cnt = min(ccnt[c], CCAP);
    const int chunk = (cnt + 7) / 8;
    const int e0 = s * chunk;
    const int e1 = min(e0 + chunk, cnt);
    if (t < FB) histL[t] = 0;
    __syncthreads();
    const uint* ce = cedges + (size_t)c * CCAP;
    for (int i = e0 + t; i < e1; i += 256)
        atomicAdd(&histL[(ce[i] & 1023u) >> 6], 1);
    __syncthreads();
    if (t < FB)
        curL[t] = histL[t] ? atomicAdd(&gcur[c * FB + t], histL[t]) : 0;
    __syncthreads();
    for (int i = e0 + t; i < e1; i += 256) {
        const uint p = ce[i];
        const uint dl = p & 1023u;
        const int f = (int)(dl >> 6);
        const int pos = atomicAdd(&curL[f], 1);
        if (pos < BCAP)
            bedges[(size_t)(c * FB + f) * BCAP + pos] = ((p >> 10) << 6) | (dl & 63u);
    }
}

// Per-bucket gather (BNODES=64): hist + scan + sort-to-node-order (int LDS
// atomics; bedges read twice, 2nd pass L2-hot), then pull with EIGHT edges in
// flight per wave (round 10 had 4 @ VGPR=12 -> MLP-limited), one coalesced
// row write per node. LDS ~9.3KB.
__global__ __launch_bounds__(512)
void bucket_gather_kernel(const uint* __restrict__ msg, const int* __restrict__ gcur,
                          const uint* __restrict__ bedges, float* __restrict__ agg,
                          int n_nodes)
{
    __shared__ int  srcL[BCAP];      // 8 KB
    __shared__ int histL[BNODES];
    __shared__ int inclL[BNODES];
    __shared__ int cursL[BNODES];

    const int t = threadIdx.x;
    const int b = blockIdx.x;
    const int cnt = min(gcur[b], BCAP);
    const uint* be = bedges + (size_t)b * BCAP;

    if (t < BNODES) histL[t] = 0;
    __syncthreads();
    for (int i = t; i < cnt; i += 512)
        atomicAdd(&histL[be[i] & 63u], 1);
    __syncthreads();
    if (t < BNODES) inclL[t] = histL[t];
    for (int off = 1; off < BNODES; off <<= 1) {
        int add = 0;
        __syncthreads();
        if (t < BNODES && t >= off) add = inclL[t - off];
        __syncthreads();
        if (t < BNODES) inclL[t] += add;
    }
    __syncthreads();
    if (t < BNODES) cursL[t] = inclL[t] - histL[t];
    __syncthreads();
    for (int i = t; i < cnt; i += 512) {
        const uint p = be[i];
        const int pos = atomicAdd(&cursL[p & 63u], 1);
        srcL[pos] = (int)(p >> 6);
    }
    __syncthreads();

    const int lane = t & 63;
    const int w = t >> 6;            // 8 waves
    for (int dl = w; dl < BNODES; dl += 8) {
        const int node = b * BNODES + dl;
        if (node >= n_nodes) break;          // wave-uniform
        const int e1 = inclL[dl];
        const int e0 = e1 - histL[dl];
        float a0 = 0.f, a1 = 0.f;
        int i = e0;
        for (; i + 8 <= e1; i += 8) {
            uint m[8];
            #pragma unroll
            for (int k = 0; k < 8; ++k)
                m[k] = msg[(size_t)srcL[i + k] * 64 + lane];
            #pragma unroll
            for (int k = 0; k < 8; ++k) {
                a0 += __uint_as_float(m[k] << 16);
                a1 += __uint_as_float(m[k] & 0xffff0000u);
            }
        }
        for (; i + 4 <= e1; i += 4) {
            uint m[4];
            #pragma unroll
            for (int k = 0; k < 4; ++k)
                m[k] = msg[(size_t)srcL[i + k] * 64 + lane];
            #pragma unroll
            for (int k = 0; k < 4; ++k) {
                a0 += __uint_as_float(m[k] << 16);
                a1 += __uint_as_float(m[k] & 0xffff0000u);
            }
        }
        for (; i < e1; ++i) {
            const uint m = msg[(size_t)srcL[i] * 64 + lane];
            a0 += __uint_as_float(m << 16);
            a1 += __uint_as_float(m & 0xffff0000u);
        }
        ((float2*)(agg + (size_t)node * DIM))[lane] = make_float2(a0, a1);
    }
}

extern "C" void kernel_launch(void* const* d_in, const int* in_sizes, int n_in,
                              void* d_out, int out_size, void* d_ws, size_t ws_size,
                              hipStream_t stream)
{
    const float* x  = (const float*)d_in[0];
    const int*   ei = (const int*)d_in[1];
    const float* Wm = (const float*)d_in[2];
    const float* bm = (const float*)d_in[3];
    const float* Wu = (const float*)d_in[4];
    const float* bu = (const float*)d_in[5];

    const int N = in_sizes[0] / DIM;   // 100000
    const int E = in_sizes[1] / 2;     // 1600000
    const int nb  = (N + BNODES - 1) / BNODES;   // 1563
    const int ncb = (N + CNODES - 1) / CNODES;   // 98

    // ws: msg 25.6MB | ccur+gcur ~8.7KB | cedges 8.0MB | bedges 12.8MB (~46.5MB)
    char* ws = (char*)d_ws;
    ushort* msg = (ushort*)ws;
    size_t o = (size_t)N * DIM * sizeof(ushort);
    int* ccur = (int*)(ws + o); o += (size_t)NCMAX * 4;
    int* gcur = (int*)(ws + o); o += (size_t)NBMAX * 4;
    o = (o + 255) & ~(size_t)255;
    uint* cedges = (uint*)(ws + o); o += (size_t)ncb * CCAP * 4;
    o = (o + 255) & ~(size_t)255;
    uint* bedges = (uint*)(ws + o);

    float* out = (float*)d_out;
    float* agg = out;                  // agg lives in d_out; lin2 runs in-place

    const int n_tiles = N / 16;

    // 0) zero cursors (ccur and gcur adjacent)
    hipMemsetAsync(ccur, 0, (size_t)(NCMAX + NBMAX) * 4, stream);

    // 1) fused: coarse partition (1024 blocks) || lin1 messages (1024 blocks)
    lin1_coarse_kernel<<<2048, 256, 0, stream>>>(x, Wm, bm, msg, n_tiles,
                                                 ei, ccur, cedges, E, ncb, 1024);

    // 2) fine partition: coarse regions -> 64-node buckets
    fine_scatter_kernel<<<ncb * 8, 256, 0, stream>>>(ccur, cedges, gcur, bedges, ncb);

    // 3) per-bucket LDS sort + pull gather (8-deep MLP) -> d_out
    bucket_gather_kernel<<<nb, 512, 0, stream>>>((const uint*)msg, gcur, bedges, agg, N);

    // 4) out = relu(agg @ Wu^T + bu) + x   (in-place on d_out)
    lin2_kernel<<<1024, 256, 0, stream>>>(agg, Wu, bu, x, out, n_tiles);
}